// Round 14
// baseline (134.884 us; speedup 1.0000x reference)
//
#include <hip/hip_runtime.h>
#include <hip/hip_bf16.h>

typedef __attribute__((ext_vector_type(8))) short bf16x8;
typedef __attribute__((ext_vector_type(4))) float f32x4;
typedef __attribute__((ext_vector_type(4))) unsigned short u16x4;

#define WIDTH  2048
#define NHEADS 16
#define HDIM   128
#define BM     32

__device__ __forceinline__ unsigned short f2bf(float f) {
  union { float f; unsigned int u; } v; v.f = f;
  unsigned int u = v.u;
  unsigned int r = (u + 0x7FFFu + ((u >> 16) & 1u)) >> 16;  // RNE
  return (unsigned short)r;
}

__device__ __forceinline__ float bf2f(unsigned short s) {
  union { unsigned int u; float f; } v;
  v.u = ((unsigned int)s) << 16;
  return v.f;
}

__device__ __forceinline__ unsigned int pk_bf16(float lo, float hi) {
  __hip_bfloat162 b = __float22bfloat162_rn(make_float2(lo, hi));
  union { __hip_bfloat162 b; unsigned int u; } c; c.b = b;
  return c.u;
}

#define LOG2E 1.4426950408889634f

// Prep: transpose w_in/w_a [h][i][j] -> bf16 [h][j][i], PRE-SCALED by log2(e).
// Scaled biases; sp8 = 8*softplus(a_param)*log2(e).
__global__ __launch_bounds__(256) void prep_kernel(
    const float* __restrict__ w_in, const float* __restrict__ w_a,
    const float* __restrict__ a_param,
    const float* __restrict__ b_in, const float* __restrict__ b_a,
    unsigned short* __restrict__ wTin, unsigned short* __restrict__ wTa,
    float* __restrict__ sp8, float* __restrict__ sbi, float* __restrict__ sba) {
  int tid = blockIdx.x * 256 + threadIdx.x;    // 0 .. 16*128*128-1
  int h   = tid >> 14;
  int rem = tid & 16383;
  int j   = rem >> 7;
  int i   = rem & 127;
  int src = (h << 14) + (i << 7) + j;
  wTin[tid] = f2bf(w_in[src] * LOG2E);
  wTa[tid]  = f2bf(w_a[src] * LOG2E);
  if (tid < WIDTH) {
    float v  = a_param[tid];
    float sp = (v > 20.0f) ? v : log1pf(__expf(v));
    sp8[tid] = 8.0f * sp * LOG2E;
    sbi[tid] = b_in[tid] * LOG2E;
    sba[tid] = b_a[tid] * LOG2E;
  }
}

// R13 math, BM=32 tile: half the per-block work, half the acc registers
// (32 vs 64) -> target 6-7 waves/SIMD occupancy and 2x independent blocks.
__global__ __launch_bounds__(256, 6) void rglru_kernel(
    const float* __restrict__ x, const float* __restrict__ state,
    const float* __restrict__ sbi, const float* __restrict__ sba,
    const unsigned short* __restrict__ wTin, const unsigned short* __restrict__ wTa,
    const float* __restrict__ sp8, float* __restrict__ out) {
  __shared__ unsigned short xs[BM * HDIM];  // 8 KB bf16 x-tile, XOR-swizzled

  const int bid  = blockIdx.x;
  const int h    = bid & (NHEADS - 1);
  const int rb   = bid >> 4;
  const int t    = threadIdx.x;
  const int lane = t & 63;
  const int wid  = t >> 6;
  const int l15  = lane & 15;
  const int l4   = lane >> 4;

  // ---- stage x tile (BM x HDIM f32 -> bf16 LDS, swizzled) ----
  const float* xtile = x + (long)rb * BM * WIDTH + h * HDIM;
#pragma unroll
  for (int it = 0; it < 4; ++it) {
    int idx = it * 256 + t;            // float4 index within tile (0..1023)
    int r   = idx >> 5;                // row 0..31
    int c4  = idx & 31;                // float4 within row
    f32x4 v = __builtin_nontemporal_load(
        reinterpret_cast<const f32x4*>(xtile + (long)r * WIDTH) + c4);
    uint2 p;
    p.x = pk_bf16(v[0], v[1]);
    p.y = pk_bf16(v[2], v[3]);
    int off = (r * 256 + c4 * 8) ^ ((r & 7) << 4);
    *reinterpret_cast<uint2*>(reinterpret_cast<char*>(xs) + off) = p;
  }

  // per-column constants (bias folded into acc init)
  const int cb = h * HDIM + wid * 32 + l4 * 4;
  f32x4 bi0 = *reinterpret_cast<const f32x4*>(sbi + cb);
  f32x4 bi1 = *reinterpret_cast<const f32x4*>(sbi + cb + 16);
  f32x4 ba0 = *reinterpret_cast<const f32x4*>(sba + cb);
  f32x4 ba1 = *reinterpret_cast<const f32x4*>(sba + cb + 16);
  f32x4 sp0 = *reinterpret_cast<const f32x4*>(sp8 + cb);
  f32x4 sp1 = *reinterpret_cast<const f32x4*>(sp8 + cb + 16);

  __syncthreads();

  // ---- MFMA: acc[m][n], m in 0..1 (32 rows), n in 0..1 ----
  f32x4 acc_in[2][2], acc_a[2][2];
#pragma unroll
  for (int m = 0; m < 2; ++m) {
    acc_in[m][0] = bi0; acc_in[m][1] = bi1;
    acc_a[m][0]  = ba0; acc_a[m][1]  = ba1;
  }

  const unsigned short* wi0 = wTin + ((h * HDIM + wid * 32 + l15) * HDIM) + l4 * 8;
  const unsigned short* wi1 = wi0 + 16 * HDIM;
  const unsigned short* wa0 = wTa + ((h * HDIM + wid * 32 + l15) * HDIM) + l4 * 8;
  const unsigned short* wa1 = wa0 + 16 * HDIM;

  const int xsw = ((l15 & 7) << 4);   // per-thread swizzle bits

#pragma unroll
  for (int kk = 0; kk < 4; ++kk) {
    bf16x8 xfr[2];
#pragma unroll
    for (int m = 0; m < 2; ++m) {
      int boff = ((m * 16 + l15) * 256 + kk * 64 + l4 * 16) ^ xsw;
      xfr[m] = *reinterpret_cast<const bf16x8*>(
          reinterpret_cast<const char*>(xs) + boff);
    }
    bf16x8 win[2], wa[2];
    win[0] = *reinterpret_cast<const bf16x8*>(wi0 + kk * 32);
    win[1] = *reinterpret_cast<const bf16x8*>(wi1 + kk * 32);
    wa[0]  = *reinterpret_cast<const bf16x8*>(wa0 + kk * 32);
    wa[1]  = *reinterpret_cast<const bf16x8*>(wa1 + kk * 32);
#pragma unroll
    for (int m = 0; m < 2; ++m)
#pragma unroll
      for (int n = 0; n < 2; ++n) {
        acc_in[m][n] = __builtin_amdgcn_mfma_f32_16x16x32_bf16(
            win[n], xfr[m], acc_in[m][n], 0, 0, 0);
        acc_a[m][n] = __builtin_amdgcn_mfma_f32_16x16x32_bf16(
            wa[n], xfr[m], acc_a[m][n], 0, 0, 0);
      }
  }

  // ---- epilogue ----
  const long base = (long)(rb * BM + l15) * WIDTH + cb;
  const float* ps = state + base;
  float*       po = out + base;
  const char* pxs = reinterpret_cast<const char*>(xs);
  const int xe0 = (l15 * 256 + (wid * 32 + l4 * 4) * 2) ^ xsw;        // n=0
  const int xe1 = (l15 * 256 + (wid * 32 + 16 + l4 * 4) * 2) ^ xsw;   // n=1

#pragma unroll
  for (int m = 0; m < 2; ++m) {
#pragma unroll
    for (int n = 0; n < 2; ++n) {
      f32x4 sv = *reinterpret_cast<const f32x4*>(ps + n * 16);
      u16x4 xb = *reinterpret_cast<const u16x4*>(
          pxs + (n ? xe1 : xe0) + m * 4096);
      f32x4 sp = n ? sp1 : sp0;
      f32x4 o;
#pragma unroll
      for (int r = 0; r < 4; ++r) {
        float gx  = __builtin_amdgcn_rcpf(1.0f + exp2f(-acc_in[m][n][r]));
        float ga  = __builtin_amdgcn_rcpf(1.0f + exp2f(-acc_a[m][n][r]));
        float av  = exp2f(-ga * sp[r]);
        float sc  = sqrtf(fmaxf(1.0f - av * av, 0.0f));
        o[r] = av * sv[r] + gx * bf2f(xb[r]) * sc;
      }
      *reinterpret_cast<f32x4*>(po + n * 16) = o;
    }
    ps += 16 * WIDTH;
    po += 16 * WIDTH;
  }
}

extern "C" void kernel_launch(void* const* d_in, const int* in_sizes, int n_in,
                              void* d_out, int out_size, void* d_ws, size_t ws_size,
                              hipStream_t stream) {
  const float* x       = (const float*)d_in[0];
  const float* state   = (const float*)d_in[1];
  const float* w_in    = (const float*)d_in[2];
  const float* b_in    = (const float*)d_in[3];
  const float* w_a     = (const float*)d_in[4];
  const float* b_a     = (const float*)d_in[5];
  const float* a_param = (const float*)d_in[6];
  float* out = (float*)d_out;

  unsigned short* wTin = (unsigned short*)d_ws;
  unsigned short* wTa  = wTin + NHEADS * HDIM * HDIM;
  float*          sp8  = (float*)(wTa + NHEADS * HDIM * HDIM);
  float*          sbi  = sp8 + WIDTH;
  float*          sba  = sbi + WIDTH;

  // prep: 16*128*128 = 262144 elements -> 1024 blocks
  hipLaunchKernelGGL(prep_kernel, dim3(1024), dim3(256), 0, stream,
                     w_in, w_a, a_param, b_in, b_a, wTin, wTa, sp8, sbi, sba);

  // main: (16384/32) row-blocks * 16 heads = 8192 blocks
  hipLaunchKernelGGL(rglru_kernel, dim3(8192), dim3(256), 0, stream,
                     x, state, sbi, sba, wTin, wTa, sp8, out);
}

// Round 15
// 115.509 us; speedup vs baseline: 1.1677x; 1.1677x over previous
//
#include <hip/hip_runtime.h>
#include <hip/hip_bf16.h>

typedef __attribute__((ext_vector_type(8))) short bf16x8;
typedef __attribute__((ext_vector_type(4))) float f32x4;

#define WIDTH  2048
#define NHEADS 16
#define HDIM   128
#define BM     64

__device__ __forceinline__ unsigned short f2bf(float f) {
  union { float f; unsigned int u; } v; v.f = f;
  unsigned int u = v.u;
  unsigned int r = (u + 0x7FFFu + ((u >> 16) & 1u)) >> 16;  // RNE
  return (unsigned short)r;
}

// pack two f32 -> two bf16 (RNE) via the scalar-cast path (compiler emits
// v_cvt_pk_bf16_f32; m240: don't hand-write the asm).
__device__ __forceinline__ unsigned int pk_bf16(float lo, float hi) {
  __hip_bfloat162 b = __float22bfloat162_rn(make_float2(lo, hi));
  union { __hip_bfloat162 b; unsigned int u; } c; c.b = b;
  return c.u;
}

#define LOG2E 1.4426950408889634f

// Prep: transpose w_in/w_a [h][i][j] -> bf16 [h][j][i], PRE-SCALED by log2(e).
// Scaled biases; sp8 = 8*softplus(a_param)*log2(e).
__global__ __launch_bounds__(256) void prep_kernel(
    const float* __restrict__ w_in, const float* __restrict__ w_a,
    const float* __restrict__ a_param,
    const float* __restrict__ b_in, const float* __restrict__ b_a,
    unsigned short* __restrict__ wTin, unsigned short* __restrict__ wTa,
    float* __restrict__ sp8, float* __restrict__ sbi, float* __restrict__ sba) {
  int tid = blockIdx.x * 256 + threadIdx.x;    // 0 .. 16*128*128-1
  int h   = tid >> 14;
  int rem = tid & 16383;
  int j   = rem >> 7;
  int i   = rem & 127;
  int src = (h << 14) + (i << 7) + j;
  wTin[tid] = f2bf(w_in[src] * LOG2E);
  wTa[tid]  = f2bf(w_a[src] * LOG2E);
  if (tid < WIDTH) {
    float v  = a_param[tid];
    float sp = (v > 20.0f) ? v : log1pf(__expf(v));
    sp8[tid] = 8.0f * sp * LOG2E;
    sbi[tid] = b_in[tid] * LOG2E;
    sba[tid] = b_a[tid] * LOG2E;
  }
}

// R12 structure + async staging:
//  - x staged to LDS as F32 via global_load_lds (16B, fire-and-forget; no
//    VGPR round-trip, no cvt/ds_write on the staging critical path)
//  - linear LDS dest + inverse-swizzled per-lane SOURCE + swizzled reads
//    (chunk ^= (row&7)<<2 -> 2-way bank aliasing = free)
//  - bf16 conversion moved to fragment build (cvt_pk x4 per fragment)
//  - epilogue x now full f32 from LDS
__global__ __launch_bounds__(256, 4) void rglru_kernel(
    const float* __restrict__ x, const float* __restrict__ state,
    const float* __restrict__ sbi, const float* __restrict__ sba,
    const unsigned short* __restrict__ wTin, const unsigned short* __restrict__ wTa,
    const float* __restrict__ sp8, float* __restrict__ out) {
  __shared__ float xs[BM * HDIM];   // 32 KB f32 x-tile, source-swizzled

  const int bid  = blockIdx.x;
  const int h    = bid & (NHEADS - 1);
  const int rb   = bid >> 4;
  const int t    = threadIdx.x;
  const int lane = t & 63;
  const int wid  = t >> 6;
  const int l15  = lane & 15;
  const int l4   = lane >> 4;

  // ---- async stage: 8 x global_load_lds(16B) per thread ----
  // wave w, iter i covers LDS rows w*16 + i*2 + (lane>>5); lane&31 = 16B chunk.
  // LDS layout: row-major f32 [64][128]; chunk (r,c) holds global chunk
  // c ^ ((r&7)<<2)  (involution; applied on source here, on address at reads).
  {
    const float* xtile = x + (long)rb * BM * WIDTH + h * HDIM;
    const int rloc = lane >> 5;       // 0..1
    const int cc   = lane & 31;       // 16B chunk within row
#pragma unroll
    for (int i = 0; i < 8; ++i) {
      int r    = wid * 16 + i * 2 + rloc;
      int csrc = cc ^ ((r & 7) << 2);
      const float* src = xtile + (long)r * WIDTH + csrc * 4;
      unsigned lds_off = (unsigned)((wid * 16 + i * 2) * 512);  // wave-uniform
      __builtin_amdgcn_global_load_lds(
          (const __attribute__((address_space(1))) unsigned int*)src,
          (__attribute__((address_space(3))) unsigned int*)(
              (__attribute__((address_space(3))) char*)xs + lds_off),
          16, 0, 0);
    }
  }

  // per-column constants (bias folded into acc init) — overlap the staging
  const int cb = h * HDIM + wid * 32 + l4 * 4;
  f32x4 bi0 = *reinterpret_cast<const f32x4*>(sbi + cb);
  f32x4 bi1 = *reinterpret_cast<const f32x4*>(sbi + cb + 16);
  f32x4 ba0 = *reinterpret_cast<const f32x4*>(sba + cb);
  f32x4 ba1 = *reinterpret_cast<const f32x4*>(sba + cb + 16);
  f32x4 sp0 = *reinterpret_cast<const f32x4*>(sp8 + cb);
  f32x4 sp1 = *reinterpret_cast<const f32x4*>(sp8 + cb + 16);

  __syncthreads();   // drains the global_load_lds queue (required semantics)

  // ---- MFMA: acc[m][n] initialized with bias ----
  f32x4 acc_in[4][2], acc_a[4][2];
#pragma unroll
  for (int m = 0; m < 4; ++m) {
    acc_in[m][0] = bi0; acc_in[m][1] = bi1;
    acc_a[m][0]  = ba0; acc_a[m][1]  = ba1;
  }

  const unsigned short* wi0 = wTin + ((h * HDIM + wid * 32 + l15) * HDIM) + l4 * 8;
  const unsigned short* wi1 = wi0 + 16 * HDIM;
  const unsigned short* wa0 = wTa + ((h * HDIM + wid * 32 + l15) * HDIM) + l4 * 8;
  const unsigned short* wa1 = wa0 + 16 * HDIM;

  const char* pxs = reinterpret_cast<const char*>(xs);

#pragma unroll
  for (int kk = 0; kk < 4; ++kk) {
    bf16x8 xfr[4];
#pragma unroll
    for (int m = 0; m < 4; ++m) {
      int r  = m * 16 + l15;
      int c0 = (kk * 8 + l4 * 2) ^ ((r & 7) << 2);   // 16B chunk (even base,
      // swizzle bits >=2 -> c0,c0+1 stay adjacent)
      const f32x4* p = reinterpret_cast<const f32x4*>(pxs + r * 512 + c0 * 16);
      f32x4 lo = p[0], hi = p[1];
      union { bf16x8 v; unsigned int u[4]; } uu;
      uu.u[0] = pk_bf16(lo[0], lo[1]);
      uu.u[1] = pk_bf16(lo[2], lo[3]);
      uu.u[2] = pk_bf16(hi[0], hi[1]);
      uu.u[3] = pk_bf16(hi[2], hi[3]);
      xfr[m] = uu.v;
    }
    bf16x8 win[2], wa[2];
    win[0] = *reinterpret_cast<const bf16x8*>(wi0 + kk * 32);
    win[1] = *reinterpret_cast<const bf16x8*>(wi1 + kk * 32);
    wa[0]  = *reinterpret_cast<const bf16x8*>(wa0 + kk * 32);
    wa[1]  = *reinterpret_cast<const bf16x8*>(wa1 + kk * 32);
#pragma unroll
    for (int m = 0; m < 4; ++m)
#pragma unroll
      for (int n = 0; n < 2; ++n) {
        acc_in[m][n] = __builtin_amdgcn_mfma_f32_16x16x32_bf16(
            win[n], xfr[m], acc_in[m][n], 0, 0, 0);
        acc_a[m][n] = __builtin_amdgcn_mfma_f32_16x16x32_bf16(
            wa[n], xfr[m], acc_a[m][n], 0, 0, 0);
      }
  }

  // ---- epilogue: x from LDS (f32), state/out via running pointers ----
  const long base = (long)(rb * BM + l15) * WIDTH + cb;
  const float* ps = state + base;
  float*       po = out + base;

#pragma unroll
  for (int m = 0; m < 4; ++m) {
    const int r = m * 16 + l15;
    const int sw = (r & 7) << 2;
#pragma unroll
    for (int n = 0; n < 2; ++n) {
      f32x4 sv = *reinterpret_cast<const f32x4*>(ps + n * 16);
      int cx = (wid * 8 + n * 4 + l4) ^ sw;        // 16B chunk of x cols
      f32x4 xv = *reinterpret_cast<const f32x4*>(pxs + r * 512 + cx * 16);
      f32x4 sp = n ? sp1 : sp0;
      f32x4 o;
#pragma unroll
      for (int rr = 0; rr < 4; ++rr) {
        float gx  = __builtin_amdgcn_rcpf(1.0f + exp2f(-acc_in[m][n][rr]));
        float ga  = __builtin_amdgcn_rcpf(1.0f + exp2f(-acc_a[m][n][rr]));
        float av  = exp2f(-ga * sp[rr]);
        float sc  = sqrtf(fmaxf(1.0f - av * av, 0.0f));
        o[rr] = av * sv[rr] + gx * xv[rr] * sc;
      }
      *reinterpret_cast<f32x4*>(po + n * 16) = o;
    }
    ps += 16 * WIDTH;
    po += 16 * WIDTH;
  }
}

extern "C" void kernel_launch(void* const* d_in, const int* in_sizes, int n_in,
                              void* d_out, int out_size, void* d_ws, size_t ws_size,
                              hipStream_t stream) {
  const float* x       = (const float*)d_in[0];
  const float* state   = (const float*)d_in[1];
  const float* w_in    = (const float*)d_in[2];
  const float* b_in    = (const float*)d_in[3];
  const float* w_a     = (const float*)d_in[4];
  const float* b_a     = (const float*)d_in[5];
  const float* a_param = (const float*)d_in[6];
  float* out = (float*)d_out;

  unsigned short* wTin = (unsigned short*)d_ws;
  unsigned short* wTa  = wTin + NHEADS * HDIM * HDIM;
  float*          sp8  = (float*)(wTa + NHEADS * HDIM * HDIM);
  float*          sbi  = sp8 + WIDTH;
  float*          sba  = sbi + WIDTH;

  // prep: 16*128*128 = 262144 elements -> 1024 blocks
  hipLaunchKernelGGL(prep_kernel, dim3(1024), dim3(256), 0, stream,
                     w_in, w_a, a_param, b_in, b_a, wTin, wTa, sp8, sbi, sba);

  // main: (16384/64) row-blocks * 16 heads = 4096 blocks
  hipLaunchKernelGGL(rglru_kernel, dim3(4096), dim3(256), 0, stream,
                     x, state, sbi, sba, wTin, wTa, sp8, out);
}

// Round 16
// 104.941 us; speedup vs baseline: 1.2853x; 1.1007x over previous
//
#include <hip/hip_runtime.h>
#include <hip/hip_bf16.h>

typedef __attribute__((ext_vector_type(8))) short bf16x8;
typedef __attribute__((ext_vector_type(4))) float f32x4;
typedef __attribute__((ext_vector_type(4))) unsigned short u16x4;
typedef __attribute__((ext_vector_type(8))) unsigned short u16x8;

#define WIDTH  2048
#define NHEADS 16
#define HDIM   128
#define BM     64

__device__ __forceinline__ unsigned short f2bf(float f) {
  union { float f; unsigned int u; } v; v.f = f;
  unsigned int u = v.u;
  unsigned int r = (u + 0x7FFFu + ((u >> 16) & 1u)) >> 16;  // RNE
  return (unsigned short)r;
}

__device__ __forceinline__ float bf2f(unsigned short s) {
  union { unsigned int u; float f; } v;
  v.u = ((unsigned int)s) << 16;
  return v.f;
}

// pack two f32 -> two bf16 (RNE) via scalar-cast path (compiler emits cvt_pk)
__device__ __forceinline__ unsigned int pk_bf16(float lo, float hi) {
  __hip_bfloat162 b = __float22bfloat162_rn(make_float2(lo, hi));
  union { __hip_bfloat162 b; unsigned int u; } c; c.b = b;
  return c.u;
}

#define LOG2E 1.4426950408889634f

// Prep (coalesced): blocks 0..63 transpose one 32-row slab of one head for
// BOTH weight matrices via an LDS tile (coalesced f32 reads, 16B bf16 writes).
// Blocks 64..71: params (sp8/sbi/sba), 2048 threads exactly.
__global__ __launch_bounds__(256) void prep_kernel(
    const float* __restrict__ w_in, const float* __restrict__ w_a,
    const float* __restrict__ a_param,
    const float* __restrict__ b_in, const float* __restrict__ b_a,
    unsigned short* __restrict__ wTin, unsigned short* __restrict__ wTa,
    float* __restrict__ sp8, float* __restrict__ sbi, float* __restrict__ sba) {
  const int b = blockIdx.x;
  if (b >= 64) {
    int tid = (b - 64) * 256 + threadIdx.x;   // 0..2047
    float v  = a_param[tid];
    float sp = (v > 20.0f) ? v : log1pf(__expf(v));
    sp8[tid] = 8.0f * sp * LOG2E;
    sbi[tid] = b_in[tid] * LOG2E;
    sba[tid] = b_a[tid] * LOG2E;
    return;
  }
  const int h  = b >> 2;
  const int i0 = (b & 3) * 32;                // input-dim slab
  __shared__ unsigned short tl[2][32][136];   // +8 pad

  const float* s0 = w_in + h * 16384 + i0 * 128;
  const float* s1 = w_a  + h * 16384 + i0 * 128;
#pragma unroll
  for (int it = 0; it < 4; ++it) {
    int e = it * 1024 + threadIdx.x * 4;      // 4 consecutive f32
    int r = e >> 7, c = e & 127;
    f32x4 v0 = *reinterpret_cast<const f32x4*>(s0 + r * 128 + c);
    f32x4 v1 = *reinterpret_cast<const f32x4*>(s1 + r * 128 + c);
#pragma unroll
    for (int k = 0; k < 4; ++k) {
      tl[0][r][c + k] = f2bf(v0[k] * LOG2E);
      tl[1][r][c + k] = f2bf(v1[k] * LOG2E);
    }
  }
  __syncthreads();

  const int j  = threadIdx.x >> 1;            // out col 0..127
  const int ih = (threadIdx.x & 1) * 16;      // i-half within slab
  u16x8 o0a, o0b, o1a, o1b;
#pragma unroll
  for (int k = 0; k < 8; ++k) {
    o0a[k] = tl[0][ih + k][j];      o0b[k] = tl[0][ih + 8 + k][j];
    o1a[k] = tl[1][ih + k][j];      o1b[k] = tl[1][ih + 8 + k][j];
  }
  unsigned short* d0 = wTin + h * 16384 + j * 128 + i0 + ih;
  unsigned short* d1 = wTa  + h * 16384 + j * 128 + i0 + ih;
  *reinterpret_cast<u16x8*>(d0)     = o0a;
  *reinterpret_cast<u16x8*>(d0 + 8) = o0b;
  *reinterpret_cast<u16x8*>(d1)     = o1a;
  *reinterpret_cast<u16x8*>(d1 + 8) = o1b;
}

// Main: R12 structure (best 102.5us) + bijective XCD row-clustering swizzle:
// XCD k (bid%8==k) processes contiguous row range rb in [k*32*..), all heads.
__global__ __launch_bounds__(256, 4) void rglru_kernel(
    const float* __restrict__ x, const float* __restrict__ state,
    const float* __restrict__ sbi, const float* __restrict__ sba,
    const unsigned short* __restrict__ wTin, const unsigned short* __restrict__ wTa,
    const float* __restrict__ sp8, float* __restrict__ out) {
  __shared__ unsigned short xs[BM * HDIM];  // bf16 x-tile, XOR-swizzled

  const int bid0 = blockIdx.x;
  const int bid  = ((bid0 & 7) << 9) + (bid0 >> 3);   // bijective, 4096 blocks
  const int h    = bid & (NHEADS - 1);
  const int rb   = bid >> 4;
  const int t    = threadIdx.x;
  const int lane = t & 63;
  const int wid  = t >> 6;
  const int l15  = lane & 15;
  const int l4   = lane >> 4;

  // ---- stage x tile (BM x HDIM f32 -> bf16 LDS, swizzled); NT keeps x out
  // of LLC so state+out stay resident across replays ----
  const float* xtile = x + (long)rb * BM * WIDTH + h * HDIM;
#pragma unroll
  for (int it = 0; it < 8; ++it) {
    int idx = it * 256 + t;            // float4 index within tile (0..2047)
    int r   = idx >> 5;                // row 0..63
    int c4  = idx & 31;                // float4 within row
    f32x4 v = __builtin_nontemporal_load(
        reinterpret_cast<const f32x4*>(xtile + (long)r * WIDTH) + c4);
    uint2 p;
    p.x = pk_bf16(v[0], v[1]);
    p.y = pk_bf16(v[2], v[3]);
    int off = (r * 256 + c4 * 8) ^ ((r & 7) << 4);
    *reinterpret_cast<uint2*>(reinterpret_cast<char*>(xs) + off) = p;
  }

  // per-column constants (bias folded into acc init)
  const int cb = h * HDIM + wid * 32 + l4 * 4;
  f32x4 bi0 = *reinterpret_cast<const f32x4*>(sbi + cb);
  f32x4 bi1 = *reinterpret_cast<const f32x4*>(sbi + cb + 16);
  f32x4 ba0 = *reinterpret_cast<const f32x4*>(sba + cb);
  f32x4 ba1 = *reinterpret_cast<const f32x4*>(sba + cb + 16);
  f32x4 sp0 = *reinterpret_cast<const f32x4*>(sp8 + cb);
  f32x4 sp1 = *reinterpret_cast<const f32x4*>(sp8 + cb + 16);

  __syncthreads();

  // ---- MFMA: acc[m][n] initialized with bias (C-in accumulates) ----
  f32x4 acc_in[4][2], acc_a[4][2];
#pragma unroll
  for (int m = 0; m < 4; ++m) {
    acc_in[m][0] = bi0; acc_in[m][1] = bi1;
    acc_a[m][0]  = ba0; acc_a[m][1]  = ba1;
  }

  const unsigned short* wi0 = wTin + ((h * HDIM + wid * 32 + l15) * HDIM) + l4 * 8;
  const unsigned short* wi1 = wi0 + 16 * HDIM;
  const unsigned short* wa0 = wTa + ((h * HDIM + wid * 32 + l15) * HDIM) + l4 * 8;
  const unsigned short* wa1 = wa0 + 16 * HDIM;

  const int xsw = ((l15 & 7) << 4);   // per-thread swizzle bits (4..6)

#pragma unroll
  for (int kk = 0; kk < 4; ++kk) {
    bf16x8 xfr[4];
#pragma unroll
    for (int m = 0; m < 4; ++m) {
      int boff = ((m * 16 + l15) * 256 + kk * 64 + l4 * 16) ^ xsw;
      xfr[m] = *reinterpret_cast<const bf16x8*>(
          reinterpret_cast<const char*>(xs) + boff);
    }
    bf16x8 win[2], wa[2];
    win[0] = *reinterpret_cast<const bf16x8*>(wi0 + kk * 32);
    win[1] = *reinterpret_cast<const bf16x8*>(wi1 + kk * 32);
    wa[0]  = *reinterpret_cast<const bf16x8*>(wa0 + kk * 32);
    wa[1]  = *reinterpret_cast<const bf16x8*>(wa1 + kk * 32);
#pragma unroll
    for (int m = 0; m < 4; ++m)
#pragma unroll
      for (int n = 0; n < 2; ++n) {
        acc_in[m][n] = __builtin_amdgcn_mfma_f32_16x16x32_bf16(
            win[n], xfr[m], acc_in[m][n], 0, 0, 0);
        acc_a[m][n] = __builtin_amdgcn_mfma_f32_16x16x32_bf16(
            wa[n], xfr[m], acc_a[m][n], 0, 0, 0);
      }
  }

  // ---- epilogue ----
  const long base = (long)(rb * BM + l15) * WIDTH + cb;
  const float* ps = state + base;
  float*       po = out + base;
  const char* pxs = reinterpret_cast<const char*>(xs);
  // XOR applied after summing ALL low-order offsets (incl. n*32)
  const int xe0 = (l15 * 256 + (wid * 32 + l4 * 4) * 2) ^ xsw;        // n=0
  const int xe1 = (l15 * 256 + (wid * 32 + 16 + l4 * 4) * 2) ^ xsw;   // n=1

#pragma unroll
  for (int m = 0; m < 4; ++m) {
#pragma unroll
    for (int n = 0; n < 2; ++n) {
      f32x4 sv = *reinterpret_cast<const f32x4*>(ps + n * 16);
      u16x4 xb = *reinterpret_cast<const u16x4*>(
          pxs + (n ? xe1 : xe0) + m * 4096);
      f32x4 sp = n ? sp1 : sp0;
      f32x4 o;
#pragma unroll
      for (int r = 0; r < 4; ++r) {
        float gx  = __builtin_amdgcn_rcpf(1.0f + exp2f(-acc_in[m][n][r]));
        float ga  = __builtin_amdgcn_rcpf(1.0f + exp2f(-acc_a[m][n][r]));
        float av  = exp2f(-ga * sp[r]);
        float sc  = sqrtf(fmaxf(1.0f - av * av, 0.0f));
        o[r] = av * sv[r] + gx * bf2f(xb[r]) * sc;
      }
      *reinterpret_cast<f32x4*>(po + n * 16) = o;
    }
    ps += 16 * WIDTH;
    po += 16 * WIDTH;
  }
}

extern "C" void kernel_launch(void* const* d_in, const int* in_sizes, int n_in,
                              void* d_out, int out_size, void* d_ws, size_t ws_size,
                              hipStream_t stream) {
  const float* x       = (const float*)d_in[0];
  const float* state   = (const float*)d_in[1];
  const float* w_in    = (const float*)d_in[2];
  const float* b_in    = (const float*)d_in[3];
  const float* w_a     = (const float*)d_in[4];
  const float* b_a     = (const float*)d_in[5];
  const float* a_param = (const float*)d_in[6];
  float* out = (float*)d_out;

  unsigned short* wTin = (unsigned short*)d_ws;
  unsigned short* wTa  = wTin + NHEADS * HDIM * HDIM;
  float*          sp8  = (float*)(wTa + NHEADS * HDIM * HDIM);
  float*          sbi  = sp8 + WIDTH;
  float*          sba  = sbi + WIDTH;

  // prep: 64 transpose blocks (16 heads x 4 slabs) + 8 param blocks
  hipLaunchKernelGGL(prep_kernel, dim3(72), dim3(256), 0, stream,
                     w_in, w_a, a_param, b_in, b_a, wTin, wTa, sp8, sbi, sba);

  // main: 4096 blocks (XCD-swizzled inside), 256 threads
  hipLaunchKernelGGL(rglru_kernel, dim3(4096), dim3(256), 0, stream,
                     x, state, sbi, sba, wTin, wTa, sp8, out);
}

// Round 17
// 102.824 us; speedup vs baseline: 1.3118x; 1.0206x over previous
//
#include <hip/hip_runtime.h>
#include <hip/hip_bf16.h>

typedef __attribute__((ext_vector_type(8))) short bf16x8;
typedef __attribute__((ext_vector_type(4))) float f32x4;
typedef __attribute__((ext_vector_type(4))) unsigned short u16x4;
typedef __attribute__((ext_vector_type(8))) unsigned short u16x8;

#define WIDTH  2048
#define NHEADS 16
#define HDIM   128
#define BM     64

__device__ __forceinline__ unsigned short f2bf(float f) {
  union { float f; unsigned int u; } v; v.f = f;
  unsigned int u = v.u;
  unsigned int r = (u + 0x7FFFu + ((u >> 16) & 1u)) >> 16;  // RNE
  return (unsigned short)r;
}

__device__ __forceinline__ float bf2f(unsigned short s) {
  union { unsigned int u; float f; } v;
  v.u = ((unsigned int)s) << 16;
  return v.f;
}

// pack two f32 -> two bf16 (RNE) via scalar-cast path (compiler emits cvt_pk)
__device__ __forceinline__ unsigned int pk_bf16(float lo, float hi) {
  __hip_bfloat162 b = __float22bfloat162_rn(make_float2(lo, hi));
  union { __hip_bfloat162 b; unsigned int u; } c; c.b = b;
  return c.u;
}

#define LOG2E 1.4426950408889634f

// Prep (coalesced): blocks 0..63 transpose one 32-row slab of one head for
// BOTH weight matrices via an LDS tile (coalesced f32 reads, 16B bf16 writes).
// Blocks 64..71: params (sp8/sbi/sba), 2048 threads exactly.
__global__ __launch_bounds__(256) void prep_kernel(
    const float* __restrict__ w_in, const float* __restrict__ w_a,
    const float* __restrict__ a_param,
    const float* __restrict__ b_in, const float* __restrict__ b_a,
    unsigned short* __restrict__ wTin, unsigned short* __restrict__ wTa,
    float* __restrict__ sp8, float* __restrict__ sbi, float* __restrict__ sba) {
  const int b = blockIdx.x;
  if (b >= 64) {
    int tid = (b - 64) * 256 + threadIdx.x;   // 0..2047
    float v  = a_param[tid];
    float sp = (v > 20.0f) ? v : log1pf(__expf(v));
    sp8[tid] = 8.0f * sp * LOG2E;
    sbi[tid] = b_in[tid] * LOG2E;
    sba[tid] = b_a[tid] * LOG2E;
    return;
  }
  const int h  = b >> 2;
  const int i0 = (b & 3) * 32;                // input-dim slab
  __shared__ unsigned short tl[2][32][136];   // +8 pad

  const float* s0 = w_in + h * 16384 + i0 * 128;
  const float* s1 = w_a  + h * 16384 + i0 * 128;
#pragma unroll
  for (int it = 0; it < 4; ++it) {
    int e = it * 1024 + threadIdx.x * 4;      // 4 consecutive f32
    int r = e >> 7, c = e & 127;
    f32x4 v0 = *reinterpret_cast<const f32x4*>(s0 + r * 128 + c);
    f32x4 v1 = *reinterpret_cast<const f32x4*>(s1 + r * 128 + c);
#pragma unroll
    for (int k = 0; k < 4; ++k) {
      tl[0][r][c + k] = f2bf(v0[k] * LOG2E);
      tl[1][r][c + k] = f2bf(v1[k] * LOG2E);
    }
  }
  __syncthreads();

  const int j  = threadIdx.x >> 1;            // out col 0..127
  const int ih = (threadIdx.x & 1) * 16;      // i-half within slab
  u16x8 o0a, o0b, o1a, o1b;
#pragma unroll
  for (int k = 0; k < 8; ++k) {
    o0a[k] = tl[0][ih + k][j];      o0b[k] = tl[0][ih + 8 + k][j];
    o1a[k] = tl[1][ih + k][j];      o1b[k] = tl[1][ih + 8 + k][j];
  }
  unsigned short* d0 = wTin + h * 16384 + j * 128 + i0 + ih;
  unsigned short* d1 = wTa  + h * 16384 + j * 128 + i0 + ih;
  *reinterpret_cast<u16x8*>(d0)     = o0a;
  *reinterpret_cast<u16x8*>(d0 + 8) = o0b;
  *reinterpret_cast<u16x8*>(d1)     = o1a;
  *reinterpret_cast<u16x8*>(d1 + 8) = o1b;
}

// Main: R12 structure (best 102.5us), default blockIdx mapping (R16 showed
// XCD row-clustering hurts LLC locality for this op).
__global__ __launch_bounds__(256, 4) void rglru_kernel(
    const float* __restrict__ x, const float* __restrict__ state,
    const float* __restrict__ sbi, const float* __restrict__ sba,
    const unsigned short* __restrict__ wTin, const unsigned short* __restrict__ wTa,
    const float* __restrict__ sp8, float* __restrict__ out) {
  __shared__ unsigned short xs[BM * HDIM];  // bf16 x-tile, XOR-swizzled

  const int bid  = blockIdx.x;
  const int h    = bid & (NHEADS - 1);
  const int rb   = bid >> 4;
  const int t    = threadIdx.x;
  const int lane = t & 63;
  const int wid  = t >> 6;
  const int l15  = lane & 15;
  const int l4   = lane >> 4;

  // ---- stage x tile (BM x HDIM f32 -> bf16 LDS, swizzled); NT keeps x out
  // of LLC so state+out stay resident across replays ----
  const float* xtile = x + (long)rb * BM * WIDTH + h * HDIM;
#pragma unroll
  for (int it = 0; it < 8; ++it) {
    int idx = it * 256 + t;            // float4 index within tile (0..2047)
    int r   = idx >> 5;                // row 0..63
    int c4  = idx & 31;                // float4 within row
    f32x4 v = __builtin_nontemporal_load(
        reinterpret_cast<const f32x4*>(xtile + (long)r * WIDTH) + c4);
    uint2 p;
    p.x = pk_bf16(v[0], v[1]);
    p.y = pk_bf16(v[2], v[3]);
    int off = (r * 256 + c4 * 8) ^ ((r & 7) << 4);
    *reinterpret_cast<uint2*>(reinterpret_cast<char*>(xs) + off) = p;
  }

  // per-column constants (bias folded into acc init)
  const int cb = h * HDIM + wid * 32 + l4 * 4;
  f32x4 bi0 = *reinterpret_cast<const f32x4*>(sbi + cb);
  f32x4 bi1 = *reinterpret_cast<const f32x4*>(sbi + cb + 16);
  f32x4 ba0 = *reinterpret_cast<const f32x4*>(sba + cb);
  f32x4 ba1 = *reinterpret_cast<const f32x4*>(sba + cb + 16);
  f32x4 sp0 = *reinterpret_cast<const f32x4*>(sp8 + cb);
  f32x4 sp1 = *reinterpret_cast<const f32x4*>(sp8 + cb + 16);

  __syncthreads();

  // ---- MFMA: acc[m][n] initialized with bias (C-in accumulates) ----
  f32x4 acc_in[4][2], acc_a[4][2];
#pragma unroll
  for (int m = 0; m < 4; ++m) {
    acc_in[m][0] = bi0; acc_in[m][1] = bi1;
    acc_a[m][0]  = ba0; acc_a[m][1]  = ba1;
  }

  const unsigned short* wi0 = wTin + ((h * HDIM + wid * 32 + l15) * HDIM) + l4 * 8;
  const unsigned short* wi1 = wi0 + 16 * HDIM;
  const unsigned short* wa0 = wTa + ((h * HDIM + wid * 32 + l15) * HDIM) + l4 * 8;
  const unsigned short* wa1 = wa0 + 16 * HDIM;

  const int xsw = ((l15 & 7) << 4);   // per-thread swizzle bits (4..6)

#pragma unroll
  for (int kk = 0; kk < 4; ++kk) {
    bf16x8 xfr[4];
#pragma unroll
    for (int m = 0; m < 4; ++m) {
      int boff = ((m * 16 + l15) * 256 + kk * 64 + l4 * 16) ^ xsw;
      xfr[m] = *reinterpret_cast<const bf16x8*>(
          reinterpret_cast<const char*>(xs) + boff);
    }
    bf16x8 win[2], wa[2];
    win[0] = *reinterpret_cast<const bf16x8*>(wi0 + kk * 32);
    win[1] = *reinterpret_cast<const bf16x8*>(wi1 + kk * 32);
    wa[0]  = *reinterpret_cast<const bf16x8*>(wa0 + kk * 32);
    wa[1]  = *reinterpret_cast<const bf16x8*>(wa1 + kk * 32);
#pragma unroll
    for (int m = 0; m < 4; ++m)
#pragma unroll
      for (int n = 0; n < 2; ++n) {
        acc_in[m][n] = __builtin_amdgcn_mfma_f32_16x16x32_bf16(
            win[n], xfr[m], acc_in[m][n], 0, 0, 0);
        acc_a[m][n] = __builtin_amdgcn_mfma_f32_16x16x32_bf16(
            wa[n], xfr[m], acc_a[m][n], 0, 0, 0);
      }
  }

  // ---- epilogue ----
  const long base = (long)(rb * BM + l15) * WIDTH + cb;
  const float* ps = state + base;
  float*       po = out + base;
  const char* pxs = reinterpret_cast<const char*>(xs);
  // XOR applied after summing ALL low-order offsets (incl. n*32)
  const int xe0 = (l15 * 256 + (wid * 32 + l4 * 4) * 2) ^ xsw;        // n=0
  const int xe1 = (l15 * 256 + (wid * 32 + 16 + l4 * 4) * 2) ^ xsw;   // n=1

#pragma unroll
  for (int m = 0; m < 4; ++m) {
#pragma unroll
    for (int n = 0; n < 2; ++n) {
      f32x4 sv = *reinterpret_cast<const f32x4*>(ps + n * 16);
      u16x4 xb = *reinterpret_cast<const u16x4*>(
          pxs + (n ? xe1 : xe0) + m * 4096);
      f32x4 sp = n ? sp1 : sp0;
      f32x4 o;
#pragma unroll
      for (int r = 0; r < 4; ++r) {
        float gx  = __builtin_amdgcn_rcpf(1.0f + exp2f(-acc_in[m][n][r]));
        float ga  = __builtin_amdgcn_rcpf(1.0f + exp2f(-acc_a[m][n][r]));
        float av  = exp2f(-ga * sp[r]);
        float sc  = sqrtf(fmaxf(1.0f - av * av, 0.0f));
        o[r] = av * sv[r] + gx * bf2f(xb[r]) * sc;
      }
      *reinterpret_cast<f32x4*>(po + n * 16) = o;
    }
    ps += 16 * WIDTH;
    po += 16 * WIDTH;
  }
}

extern "C" void kernel_launch(void* const* d_in, const int* in_sizes, int n_in,
                              void* d_out, int out_size, void* d_ws, size_t ws_size,
                              hipStream_t stream) {
  const float* x       = (const float*)d_in[0];
  const float* state   = (const float*)d_in[1];
  const float* w_in    = (const float*)d_in[2];
  const float* b_in    = (const float*)d_in[3];
  const float* w_a     = (const float*)d_in[4];
  const float* b_a     = (const float*)d_in[5];
  const float* a_param = (const float*)d_in[6];
  float* out = (float*)d_out;

  unsigned short* wTin = (unsigned short*)d_ws;
  unsigned short* wTa  = wTin + NHEADS * HDIM * HDIM;
  float*          sp8  = (float*)(wTa + NHEADS * HDIM * HDIM);
  float*          sbi  = sp8 + WIDTH;
  float*          sba  = sbi + WIDTH;

  // prep: 64 transpose blocks (16 heads x 4 slabs) + 8 param blocks
  hipLaunchKernelGGL(prep_kernel, dim3(72), dim3(256), 0, stream,
                     w_in, w_a, a_param, b_in, b_a, wTin, wTa, sp8, sbi, sba);

  // main: 4096 blocks, 256 threads (R12 structure)
  hipLaunchKernelGGL(rglru_kernel, dim3(4096), dim3(256), 0, stream,
                     x, state, sbi, sba, wTin, wTa, sp8, out);
}